// Round 9
// baseline (266.777 us; speedup 1.0000x reference)
//
#include <hip/hip_runtime.h>
#include <hip/hip_bf16.h>

typedef unsigned short ushort_t;
typedef unsigned int uint_t;
typedef __attribute__((ext_vector_type(8))) short short8;
typedef __attribute__((ext_vector_type(4))) float float4v;
typedef __attribute__((ext_vector_type(4))) uint_t uint4v;

#define NLAT 2048
#define DLAT 64

// d_ws layout (ushort units): [0..127] flag area (int at byte 0), then packed weights
#define PW_BASE 128
#define PW0_OFF 0        // layer0: KT=7 -> 7*16*64*8 = 57344 ushorts
#define PW1_OFF 57344    // KT=8 -> 65536 each
#define PW2_OFF 122880
#define PW3_OFF 188416

__device__ __forceinline__ float b2f(ushort_t u) {
  union { uint_t i; float f; } v; v.i = ((uint_t)u) << 16; return v.f;
}
__device__ __forceinline__ ushort_t f2b(float f) {
  uint_t x = __float_as_uint(f);
  uint_t r = (x + 0x7fffu + ((x >> 16) & 1u)) >> 16;   // RNE
  return (ushort_t)r;
}
__device__ __forceinline__ uint_t pack2(float lo, float hi) {
  float2 t; t.x = lo; t.y = hi;
  union { __hip_bfloat162 h; uint_t u; } cv;
  cv.h = __float22bfloat162_rn(t);
  return cv.u;
}
__device__ __forceinline__ int imin(int a, int b) { return a < b ? a : b; }
__device__ __forceinline__ int imax(int a, int b) { return a > b ? a : b; }

__device__ __forceinline__ float ldv(const float* p, long i)    { return p[i]; }
__device__ __forceinline__ float ldv(const ushort_t* p, long i) { return b2f(p[i]); }
__device__ __forceinline__ void stv(float* p, long i, float v)    { p[i] = v; }
__device__ __forceinline__ void stv(ushort_t* p, long i, float v) { p[i] = f2b(v); }

__device__ __forceinline__ float4 load4f(const float* p) { return *(const float4*)p; }
__device__ __forceinline__ float4 load4f(const ushort_t* p) {
  uint2 u = *(const uint2*)p;
  float4 r;
  r.x = b2f((ushort_t)(u.x & 0xffffu)); r.y = b2f((ushort_t)(u.x >> 16));
  r.z = b2f((ushort_t)(u.y & 0xffffu)); r.w = b2f((ushort_t)(u.y >> 16));
  return r;
}

// --- forced-schedule primitives ---------------------------------------------
__device__ __forceinline__ void aload(short8& dst, const ushort_t* a) {
  asm volatile("global_load_dwordx4 %0, %1, off" : "=v"(dst) : "v"(a));
}
__device__ __forceinline__ void dsread(short8& dst, const ushort_t* p) {
  asm volatile("ds_read_b128 %0, %1"
               : "=v"(dst)
               : "v"((const __attribute__((address_space(3))) ushort_t*)p));
}
template <int N>
__device__ __forceinline__ void vmwait() {
  if constexpr (N == 0)      asm volatile("s_waitcnt vmcnt(0)" ::: "memory");
  else                       asm volatile("s_waitcnt vmcnt(4)" ::: "memory");
}
__device__ __forceinline__ void lgwait0() {
  asm volatile("s_waitcnt lgkmcnt(0)" ::: "memory");
}

// ---------------------------------------------------------------------------
// Runtime dtype probe: flag=1 -> fp32 inputs, flag=0 -> bf16
// ---------------------------------------------------------------------------
__global__ void detect_mode(const ushort_t* __restrict__ lat, int* __restrict__ flag) {
  if (threadIdx.x == 0) *flag = 0;
  __syncthreads();
  int big = 0;
  for (int i = threadIdx.x; i < 1024; i += 64) {
    float v = b2f(lat[i]);
    if (!(fabsf(v) < 1e5f)) big = 1;
  }
  if (__any(big) && threadIdx.x == 0) *flag = 1;
}

// ---------------------------------------------------------------------------
// Pack weights as MFMA A-fragments (A = W^T, m = chan_out), sigma k-permuted:
//   element j of frag(mt,kt,lane) = W[sigma][mt*16 + (lane&15)]
//   sigma = 32*kt + 16*(j>>2) + 4*(lane>>4) + (j&3)
// Layer 0: sigma indexes [sampled(192) | coord | pe(12) | pad->224].
// Merged: ONE dispatch, runtime dtype branch (block-uniform).
// ---------------------------------------------------------------------------
template <typename TI>
__device__ __forceinline__ void pack_body(const TI* __restrict__ W0, const TI* __restrict__ W1,
                                          const TI* __restrict__ W2, const TI* __restrict__ W3,
                                          ushort_t* __restrict__ pw)
{
  int g = blockIdx.x * blockDim.x + threadIdx.x;
  if (g >= 31 * 1024) return;
  int lane = g & 63, q = lane >> 4;
  int mt   = (g >> 6) & 15;
  int ktg  = g >> 10;                       // 0..30
  const TI* W; ushort_t* dst; int kt, KT; bool isw0 = false;
  if (ktg < 7)       { W = W0; dst = pw + PW0_OFF; kt = ktg;      KT = 7; isw0 = true; }
  else if (ktg < 15) { W = W1; dst = pw + PW1_OFF; kt = ktg - 7;  KT = 8; }
  else if (ktg < 23) { W = W2; dst = pw + PW2_OFF; kt = ktg - 15; KT = 8; }
  else               { W = W3; dst = pw + PW3_OFF; kt = ktg - 23; KT = 8; }
  int col = mt * 16 + (lane & 15);
  uint_t words[4];
#pragma unroll
  for (int h = 0; h < 4; ++h) {
    ushort_t vv[2];
#pragma unroll
    for (int e = 0; e < 2; ++e) {
      int j = 2 * h + e;
      int f = 32 * kt + 16 * (j >> 2) + 4 * q + (j & 3);
      int row = f;
      if (isw0) row = (f < 192) ? (13 + f) : (f == 192 ? 0 : (f <= 204 ? f - 192 : -1));
      vv[e] = (row >= 0) ? f2b(ldv(W, (long)row * 256 + col)) : (ushort_t)0;
    }
    words[h] = (uint_t)vv[0] | ((uint_t)vv[1] << 16);
  }
  uint4 o; o.x = words[0]; o.y = words[1]; o.z = words[2]; o.w = words[3];
  *(uint4*)(dst + ((size_t)(mt * KT + kt) * 64 + lane) * 8) = o;
}

__global__ void pack_w_u(const void* W0, const void* W1, const void* W2, const void* W3,
                         ushort_t* __restrict__ pw, const int* __restrict__ flag)
{
  if (*flag == 1)
    pack_body<float>((const float*)W0, (const float*)W1, (const float*)W2, (const float*)W3, pw);
  else
    pack_body<ushort_t>((const ushort_t*)W0, (const ushort_t*)W1, (const ushort_t*)W2, (const ushort_t*)W3, pw);
}

// ---------------------------------------------------------------------------
// R9: WIDE TILE (4mt x 8nt). The per-CU cycle model (validated against R8:
// matrix+DS+VMEM ~= observed) says the pipes sum and only operand-bytes/FLOP
// moves the total. acc[4][8] (128 AGPR): per kt, 4 A + 8 B frags (12 KB) feed
// 32 MFMAs -> 0.375 KB/MFMA (was 0.5), 25% less operand traffic, 2x fewer
// loads/waits, 512-cy MFMA bursts. B single-buffered (lgkmcnt(0) before the
// burst — the proven 8-phase GEMM pattern); A asm-ring distance 1, vmcnt(4),
// next-layer A(0) issued before the convert barriers (crosses in flight).
// In-place 64 KB act, 2 raw barriers/layer. sigma pack / convert mapping /
// feature build reused verbatim.
// ---------------------------------------------------------------------------
template <int KT, int BASE, int NEXTKT>
__device__ __forceinline__ void run_layer_w(const ushort_t* __restrict__ pwl,
                                            const ushort_t* __restrict__ pwl_next,
                                            float4v (&acc)[4][8],
                                            const ushort_t* __restrict__ act,
                                            int lane, int wv, short8 (&Ar)[2][4])
{
#pragma unroll
  for (int m = 0; m < 4; ++m)
#pragma unroll
    for (int i = 0; i < 8; ++i)
      acc[m][i] = (float4v){0.f, 0.f, 0.f, 0.f};

  const ushort_t* abase = pwl + (((size_t)(4 * wv) * KT) * 64 + lane) * 8;
  const ushort_t* nbase = nullptr;
  if constexpr (NEXTKT > 0)
    nbase = pwl_next + (((size_t)(4 * wv) * NEXTKT) * 64 + lane) * 8;

  // slot i <-> pt-tile t=(2wv+i)&7 ; offset = t*4096 + kt*512 + lane*8 ushorts
  int boff[8];
#pragma unroll
  for (int i = 0; i < 8; ++i) boff[i] = (((2 * wv + i) & 7) << 12) + (lane << 3);

  short8 B[8];

#pragma unroll
  for (int kt = 0; kt < KT; ++kt) {
    // ---- issue A(kt+1) into ring slot (BASE+kt+1)&1 ----
    if (kt + 1 < KT) {
#pragma unroll
      for (int m = 0; m < 4; ++m)
        aload(Ar[(BASE + kt + 1) & 1][m], abase + (size_t)(m * KT + kt + 1) * 512);
    } else if constexpr (NEXTKT > 0) {
#pragma unroll
      for (int m = 0; m < 4; ++m)
        aload(Ar[(BASE + kt + 1) & 1][m], nbase + (size_t)(m * NEXTKT) * 512);
    }
    // ---- issue B(kt): 8 dsreads ----
#pragma unroll
    for (int i = 0; i < 8; ++i) dsread(B[i], act + boff[i] + kt * 512);
    // ---- waits: B(kt) all retired; A(kt) retired (the 4 in flight = A(kt+1)) ----
    lgwait0();
    if (kt + 1 < KT || NEXTKT > 0) vmwait<4>();
    else                           vmwait<0>();
    __builtin_amdgcn_sched_barrier(0);      // rule #18: no MFMA hoist past waits
    // ---- 32-MFMA burst on A slot (BASE+kt)&1 ----
    short8 (&Ac)[4] = Ar[(BASE + kt) & 1];
    __builtin_amdgcn_s_setprio(1);
#pragma unroll
    for (int i = 0; i < 8; ++i) {
      acc[0][i] = __builtin_amdgcn_mfma_f32_16x16x32_bf16(Ac[0], B[i], acc[0][i], 0, 0, 0);
      acc[1][i] = __builtin_amdgcn_mfma_f32_16x16x32_bf16(Ac[1], B[i], acc[1][i], 0, 0, 0);
      acc[2][i] = __builtin_amdgcn_mfma_f32_16x16x32_bf16(Ac[2], B[i], acc[2][i], 0, 0, 0);
      acc[3][i] = __builtin_amdgcn_mfma_f32_16x16x32_bf16(Ac[3], B[i], acc[3][i], 0, 0, 0);
    }
    __builtin_amdgcn_s_setprio(0);
  }
}

// acc -> bias+relu+bf16 -> act IN PLACE. kt_dst = 2wv + (mt>>1), half = mt&1,
// lane slot = own lane (proven mapping); slot i -> pt-tile (2wv+i)&7
// (address-only). Caller provides the reads-done barrier; we end with the
// writes-visible barrier. lgkmcnt(0) only — A-loads stay in flight.
__device__ __forceinline__ void convert_store_ip(float4v (&acc)[4][8],
                                                 ushort_t* __restrict__ act,
                                                 const float* __restrict__ bwl,
                                                 int lane, int wv, int q)
{
#pragma unroll
  for (int p2 = 0; p2 < 2; ++p2) {
    const float4 bE = *(const float4*)&bwl[wv * 64 + p2 * 32 + 4 * q];
    const float4 bO = *(const float4*)&bwl[wv * 64 + p2 * 32 + 16 + 4 * q];
    const int kt = 2 * wv + p2;
#pragma unroll
    for (int i = 0; i < 8; ++i) {
      const int t = (2 * wv + i) & 7;       // runtime, address-only
      const float4v& aE = acc[2 * p2][i];
      const float4v& aO = acc[2 * p2 + 1][i];
      uint4 o;
      o.x = pack2(fmaxf(aE[0] + bE.x, 0.f), fmaxf(aE[1] + bE.y, 0.f));
      o.y = pack2(fmaxf(aE[2] + bE.z, 0.f), fmaxf(aE[3] + bE.w, 0.f));
      o.z = pack2(fmaxf(aO[0] + bO.x, 0.f), fmaxf(aO[1] + bO.y, 0.f));
      o.w = pack2(fmaxf(aO[2] + bO.z, 0.f), fmaxf(aO[3] + bO.w, 0.f));
      *(uint4*)&act[(size_t)(t << 12) + kt * 512 + (lane << 3)] = o;
    }
  }
  lgwait0();
  __builtin_amdgcn_s_barrier();             // writes visible before next layer
}

// ---------------------------------------------------------------------------
// Fused body. 256 threads = 4 waves, 128 points/block, grid 2048.
// LDS ~69.1 KB -> 2 blocks/CU. Regs: acc 128 AGPR + arch ~110 (A-ring 32,
// B 32, addrs) = ~238 unified -> 8 waves/CU (2/SIMD).
// ---------------------------------------------------------------------------
template <typename TI>
__device__ __forceinline__ void fused_body(
    const TI* __restrict__ coord, const TI* __restrict__ latent,
    const TI* __restrict__ bias0, const TI* __restrict__ bias1,
    const TI* __restrict__ bias2, const TI* __restrict__ bias3,
    const TI* __restrict__ W4,    const TI* __restrict__ b4,
    const ushort_t* __restrict__ pw, TI* __restrict__ out,
    ushort_t* act, float* bw)
{
  const int tid  = threadIdx.x;
  const int lane = tid & 63, q = lane >> 4, m15 = lane & 15;
  const int wv   = tid >> 6;                               // 0..3
  const long pbase = (long)blockIdx.x * 128 + wv * 32 + m15;  // group g adds 16

  // ---- bias/w4 table ----
  for (int i = tid; i < 1281; i += 256) {
    float v;
    if (i < 256)       v = ldv(bias0, i);
    else if (i < 512)  v = ldv(bias1, i - 256);
    else if (i < 768)  v = ldv(bias2, i - 512);
    else if (i < 1024) v = ldv(bias3, i - 768);
    else if (i < 1280) v = ldv(W4, i - 1024);
    else               v = ldv(b4, 0);
    bw[i] = v;
  }

  // ---- feature build (2 pts/thread); wave wv owns pt-tiles 2wv, 2wv+1 ----
#pragma unroll
  for (int g = 0; g < 2; ++g) {
    const long p = pbase + g * 16;
    float c   = ldv(coord, p);
    float ixv = c * 2048.0f - 0.5f;
    float x0f = floorf(ixv);
    float t   = ixv - x0f;
    int   x0  = (int)x0f;
    int   i0  = imin(imax(x0, 0), NLAT - 1);
    int   i1  = imin(imax(x0 + 1, 0), NLAT - 1);
    float w0 = 1.0f - t, w1 = t;
    int rows0[3] = { imax(i0 - 1, 0), i0, imin(i0 + 1, NLAT - 1) };
    int rows1[3] = { imax(i1 - 1, 0), i1, imin(i1 + 1, NLAT - 1) };
    const TI* lat = latent + (size_t)(p >> 15) * (NLAT * DLAT);
    uint4v hu[7];
#pragma unroll
    for (int tb = 0; tb < 12; ++tb) {
      int region = tb >> 2;
      int d0 = 16 * (tb & 3) + 4 * q;
      float4 a = load4f(lat + (long)rows0[region] * DLAT + d0);
      float4 b = load4f(lat + (long)rows1[region] * DLAT + d0);
      hu[tb >> 1][(tb & 1) * 2 + 0] = pack2(w0 * a.x + w1 * b.x, w0 * a.y + w1 * b.y);
      hu[tb >> 1][(tb & 1) * 2 + 1] = pack2(w0 * a.z + w1 * b.z, w0 * a.w + w1 * b.w);
    }
    float pv[4];
#pragma unroll
    for (int s = 0; s < 4; ++s) {
      int f = 192 + 4 * q + s;
      float v = 0.0f;
      if (f == 192) v = c;
      else if (f <= 204) {
        int i = f - 193;
        float fr = (float)(1 << (i >> 1));
        float ang = c * fr;
        v = (i & 1) ? __cosf(ang) : __sinf(ang);
      }
      pv[s] = v;
    }
    hu[6][0] = pack2(pv[0], pv[1]);
    hu[6][1] = pack2(pv[2], pv[3]);
    hu[6][2] = 0; hu[6][3] = 0;

    const int pt = 2 * wv + g;
#pragma unroll
    for (int kt = 0; kt < 7; ++kt)
      *(uint4v*)&act[((size_t)pt << 12) + kt * 512 + (lane << 3)] = hu[kt];
  }
  __syncthreads();   // features + bw ready; vm/lgkm drained -> clean counts

  // ---- prologue: A(0) into ring slot 0 (4 in flight) ----
  short8 Ar[2][4];
  {
    const ushort_t* abase = pw + PW0_OFF + (((size_t)(4 * wv) * 7) * 64 + lane) * 8;
#pragma unroll
    for (int m = 0; m < 4; ++m)
      aload(Ar[0][m], abase + (size_t)(m * 7) * 512);
  }

  float4v acc[4][8];

  run_layer_w<7, 0, 8>(pw + PW0_OFF, pw + PW1_OFF, acc, act, lane, wv, Ar);
  __builtin_amdgcn_s_barrier();                      // all act reads done
  convert_store_ip(acc, act, bw + 0 * 256, lane, wv, q);
  run_layer_w<8, 1, 8>(pw + PW1_OFF, pw + PW2_OFF, acc, act, lane, wv, Ar);
  __builtin_amdgcn_s_barrier();
  convert_store_ip(acc, act, bw + 1 * 256, lane, wv, q);
  run_layer_w<8, 1, 8>(pw + PW2_OFF, pw + PW3_OFF, acc, act, lane, wv, Ar);
  __builtin_amdgcn_s_barrier();
  convert_store_ip(acc, act, bw + 2 * 256, lane, wv, q);
  run_layer_w<8, 1, 0>(pw + PW3_OFF, nullptr,      acc, act, lane, wv, Ar);
  // last layer ends with vmwait<0>/lgkmcnt(0) -> all asm ops retired

  // ---- final: bias3+relu fused with dot against w4 (wave: 64 chans x 8 tiles) ----
  float psum[8];
#pragma unroll
  for (int i = 0; i < 8; ++i) psum[i] = 0.f;
#pragma unroll
  for (int m = 0; m < 4; ++m) {
    const float4 b3v = *(const float4*)&bw[3 * 256 + wv * 64 + m * 16 + 4 * q];
    const float4 w4v = *(const float4*)&bw[1024 + wv * 64 + m * 16 + 4 * q];
#pragma unroll
    for (int i = 0; i < 8; ++i) {
      float v;
      v = fmaxf(acc[m][i][0] + b3v.x, 0.f); psum[i] += v * w4v.x;
      v = fmaxf(acc[m][i][1] + b3v.y, 0.f); psum[i] += v * w4v.y;
      v = fmaxf(acc[m][i][2] + b3v.z, 0.f); psum[i] += v * w4v.z;
      v = fmaxf(acc[m][i][3] + b3v.w, 0.f); psum[i] += v * w4v.w;
    }
  }
#pragma unroll
  for (int i = 0; i < 8; ++i) {
    psum[i] += __shfl_xor(psum[i], 16, 64);
    psum[i] += __shfl_xor(psum[i], 32, 64);
  }

  asm volatile("" ::: "memory");
  __builtin_amdgcn_s_barrier();   // all act reads retired -> reuse as scratch
  float* part = (float*)act;      // [wv][128] partials
  if (lane < 16) {
#pragma unroll
    for (int i = 0; i < 8; ++i) {
      const int t = (2 * wv + i) & 7;
      part[wv * 128 + t * 16 + lane] = psum[i];
    }
  }
  __syncthreads();
  if (tid < 128) {
    float s = part[tid] + part[128 + tid] + part[256 + tid] + part[384 + tid]
            + bw[1280];
    stv(out, (long)blockIdx.x * 128 + tid, s);
  }
}

// Merged kernel: ONE dispatch, block-uniform runtime dtype branch.
__global__ __launch_bounds__(256, 2) void lisa_fused_u(
    const void* coord, const void* latent,
    const void* bias0, const void* bias1, const void* bias2, const void* bias3,
    const void* W4,    const void* b4,
    const ushort_t* __restrict__ pw, void* out, const int* __restrict__ flag)
{
  __shared__ __align__(16) ushort_t act[8 * 8 * 64 * 8];   // 64 KB, 8 pt-tiles
  __shared__ __align__(16) float bw[4 * 256 + 256 + 1];

  if (*flag == 1)
    fused_body<float>((const float*)coord, (const float*)latent,
                      (const float*)bias0, (const float*)bias1,
                      (const float*)bias2, (const float*)bias3,
                      (const float*)W4, (const float*)b4,
                      pw, (float*)out, act, bw);
  else
    fused_body<ushort_t>((const ushort_t*)coord, (const ushort_t*)latent,
                         (const ushort_t*)bias0, (const ushort_t*)bias1,
                         (const ushort_t*)bias2, (const ushort_t*)bias3,
                         (const ushort_t*)W4, (const ushort_t*)b4,
                         pw, (ushort_t*)out, act, bw);
}

extern "C" void kernel_launch(void* const* d_in, const int* in_sizes, int n_in,
                              void* d_out, int out_size, void* d_ws, size_t ws_size,
                              hipStream_t stream) {
  int* flag = (int*)d_ws;
  ushort_t* pw = (ushort_t*)d_ws + PW_BASE;

  detect_mode<<<1, 64, 0, stream>>>((const ushort_t*)d_in[1], flag);

  pack_w_u<<<62, 512, 0, stream>>>(d_in[2], d_in[4], d_in[6], d_in[8], pw, flag);

  lisa_fused_u<<<2048, 256, 0, stream>>>(
      d_in[0], d_in[1], d_in[3], d_in[5], d_in[7], d_in[9],
      d_in[10], d_in[11], pw, d_out, flag);
}